// Round 1
// baseline (121.206 us; speedup 1.0000x reference)
//
#include <hip/hip_runtime.h>

// Problem constants (from reference): N=131072, D=512, C=64, CHUNK=8
#define NCHUNK 16384          // N / 8
#define NC     8388608        // N * C
#define ALPHA  0.1f

// One wave (64 lanes) per 8x512 chunk. Lane l holds elements [4l,4l+4) and
// [256+4l, 256+4l+4) of each of the 8 rows (two coalesced float4 loads/row).
__global__ __launch_bounds__(256) void feat_kernel(const float* __restrict__ feat,
                                                   float* __restrict__ out) {
    const int wave = threadIdx.x >> 6;
    const int lane = threadIdx.x & 63;
    const int chunk = blockIdx.x * 4 + wave;

    const float4* base = (const float4*)(feat + (size_t)chunk * 8 * 512);

    float a[8][8];
    #pragma unroll
    for (int i = 0; i < 8; ++i) {
        float4 v1 = base[i * 128 + lane];        // d in [4l, 4l+4)
        float4 v2 = base[i * 128 + 64 + lane];   // d in [256+4l, 256+4l+4)
        a[i][0] = v1.x; a[i][1] = v1.y; a[i][2] = v1.z; a[i][3] = v1.w;
        a[i][4] = v2.x; a[i][5] = v2.y; a[i][6] = v2.z; a[i][7] = v2.w;
    }

    // 36 upper-triangular (incl. diagonal) per-lane partial dot products.
    float p[36];
    #pragma unroll
    for (int i = 0; i < 8; ++i) {
        #pragma unroll
        for (int j = i; j < 8; ++j) {
            const int idx = 8 * i - (i * (i - 1)) / 2 + (j - i); // row-start + offset
            float s = 0.f;
            #pragma unroll
            for (int k = 0; k < 8; ++k) s = fmaf(a[i][k], a[j][k], s);
            p[idx] = s;
        }
    }

    // Full-wave butterfly reduction of all 36 partials.
    #pragma unroll
    for (int off = 1; off < 64; off <<= 1) {
        #pragma unroll
        for (int k = 0; k < 36; ++k) p[k] += __shfl_xor(p[k], off);
    }

    __shared__ float bsum[4];
    if (lane == 0) {
        const int diag[8] = {0, 8, 15, 21, 26, 30, 33, 35};
        float rn[8];
        #pragma unroll
        for (int i = 0; i < 8; ++i) rn[i] = rsqrtf(p[diag[i]]);
        // sum over 28 strict-upper pairs of sim = p_ij * rn_i * rn_j
        float acc = 0.f;
        #pragma unroll
        for (int i = 0; i < 8; ++i) {
            #pragma unroll
            for (int j = i + 1; j < 8; ++j) {
                const int idx = 8 * i - (i * (i - 1)) / 2 + (j - i);
                acc = fmaf(p[idx], rn[i] * rn[j], acc);
            }
        }
        bsum[wave] = 28.0f - acc;   // sum of (1 - sim) over 28 pairs
    }
    __syncthreads();
    if (threadIdx.x == 0) {
        float t = (bsum[0] + bsum[1]) + (bsum[2] + bsum[3]);
        atomicAdd(out, ALPHA * t);
    }
}

__global__ __launch_bounds__(256) void mse_kernel(const float* __restrict__ pred,
                                                  const float* __restrict__ tgt,
                                                  float* __restrict__ out) {
    const float4* p4 = (const float4*)pred;
    const float4* t4 = (const float4*)tgt;
    const int n4 = NC / 4;
    float s = 0.f;
    for (int i = blockIdx.x * blockDim.x + threadIdx.x; i < n4;
         i += gridDim.x * blockDim.x) {
        float4 a = p4[i], b = t4[i];
        float dx = a.x - b.x, dy = a.y - b.y, dz = a.z - b.z, dw = a.w - b.w;
        s += dx * dx + dy * dy + dz * dz + dw * dw;
    }
    #pragma unroll
    for (int off = 1; off < 64; off <<= 1) s += __shfl_xor(s, off);

    __shared__ float bsum[4];
    const int lane = threadIdx.x & 63, wave = threadIdx.x >> 6;
    if (lane == 0) bsum[wave] = s;
    __syncthreads();
    if (threadIdx.x == 0) {
        float t = (bsum[0] + bsum[1]) + (bsum[2] + bsum[3]);
        atomicAdd(out, t * (1.0f / (float)NC));
    }
}

extern "C" void kernel_launch(void* const* d_in, const int* in_sizes, int n_in,
                              void* d_out, int out_size, void* d_ws, size_t ws_size,
                              hipStream_t stream) {
    const float* y_pred = (const float*)d_in[0];   // [131072, 64]
    const float* y_feat = (const float*)d_in[1];   // [131072, 512]
    const float* y_true = (const float*)d_in[2];   // [128, 1024, 64] (contiguous == flat)
    float* out = (float*)d_out;

    hipMemsetAsync(out, 0, sizeof(float), stream);

    feat_kernel<<<NCHUNK / 4, 256, 0, stream>>>(y_feat, out);
    mse_kernel<<<2048, 256, 0, stream>>>(y_pred, y_true, out);
}

// Round 2
// 102.744 us; speedup vs baseline: 1.1797x; 1.1797x over previous
//
#include <hip/hip_runtime.h>

// Problem constants: N=131072, D=512, C=64, CHUNK=8
#define NC          8388608     // N * C
#define ALPHA       0.1f
#define FEAT_BLOCKS 4096        // 4 chunks (waves) per block -> 16384 chunks
#define MSE_BLOCKS  2048
#define TOTAL_BLOCKS (FEAT_BLOCKS + MSE_BLOCKS)

// Single v_add_f32 with DPP modifier (rocPRIM wave64 reduce pattern).
template<int ctrl, int rmask>
__device__ __forceinline__ float dpp_add(float v) {
    int t = __builtin_amdgcn_update_dpp(0, __float_as_int(v), ctrl, rmask, 0xf, true);
    return v + __int_as_float(t);
}

// Full 64-lane sum; result valid in lanes 48-63 (use lane 63).
__device__ __forceinline__ float wave_reduce_dpp(float v) {
    v = dpp_add<0xB1,  0xf>(v);  // quad_perm [1,0,3,2]  (xor 1)
    v = dpp_add<0x4E,  0xf>(v);  // quad_perm [2,3,0,1]  (xor 2)
    v = dpp_add<0x141, 0xf>(v);  // row_half_mirror      (xor-ish 4)
    v = dpp_add<0x140, 0xf>(v);  // row_mirror           (xor-ish 8)
    v = dpp_add<0x142, 0xa>(v);  // row_bcast:15 -> rows 1,3
    v = dpp_add<0x143, 0xc>(v);  // row_bcast:31 -> rows 2,3
    return v;
}

__global__ __launch_bounds__(256) void fused_kernel(const float* __restrict__ feat,
                                                    const float* __restrict__ pred,
                                                    const float* __restrict__ tgt,
                                                    float* __restrict__ out) {
    const int lane = threadIdx.x & 63;
    const int wave = threadIdx.x >> 6;

    if (blockIdx.x < FEAT_BLOCKS) {
        // ---- feat_dist: one wave per 8x512 chunk ----
        const int chunk = blockIdx.x * 4 + wave;
        const float4* base = (const float4*)(feat + (size_t)chunk * 8 * 512);

        float a[8][8];
        #pragma unroll
        for (int i = 0; i < 8; ++i) {
            float4 v1 = base[i * 128 + lane];        // d in [4l, 4l+4)
            float4 v2 = base[i * 128 + 64 + lane];   // d in [256+4l, 256+4l+4)
            a[i][0] = v1.x; a[i][1] = v1.y; a[i][2] = v1.z; a[i][3] = v1.w;
            a[i][4] = v2.x; a[i][5] = v2.y; a[i][6] = v2.z; a[i][7] = v2.w;
        }

        // 36 upper-tri (incl. diag) per-lane partial dots.
        float p[36];
        #pragma unroll
        for (int i = 0; i < 8; ++i) {
            #pragma unroll
            for (int j = i; j < 8; ++j) {
                const int idx = 8 * i - (i * (i - 1)) / 2 + (j - i);
                float s = 0.f;
                #pragma unroll
                for (int k = 0; k < 8; ++k) s = fmaf(a[i][k], a[j][k], s);
                p[idx] = s;
            }
        }

        // Cross-lane sum of all 36 partials, pure-VALU DPP (no LDS pipe).
        #pragma unroll
        for (int k = 0; k < 36; ++k) p[k] = wave_reduce_dpp(p[k]);

        __shared__ float bsum[4];
        if (lane == 63) {
            const int diag[8] = {0, 8, 15, 21, 26, 30, 33, 35};
            float rn[8];
            #pragma unroll
            for (int i = 0; i < 8; ++i) rn[i] = rsqrtf(p[diag[i]]);
            float acc = 0.f;
            #pragma unroll
            for (int i = 0; i < 8; ++i) {
                #pragma unroll
                for (int j = i + 1; j < 8; ++j) {
                    const int idx = 8 * i - (i * (i - 1)) / 2 + (j - i);
                    acc = fmaf(p[idx], rn[i] * rn[j], acc);
                }
            }
            bsum[wave] = 28.0f - acc;   // sum of (1 - sim) over the 28 pairs
        }
        __syncthreads();
        if (threadIdx.x == 0) {
            float t = (bsum[0] + bsum[1]) + (bsum[2] + bsum[3]);
            atomicAdd(out, ALPHA * t);
        }
    } else {
        // ---- MSE over 8.4M elements, grid-stride float4 ----
        const int bid = blockIdx.x - FEAT_BLOCKS;
        const float4* p4 = (const float4*)pred;
        const float4* t4 = (const float4*)tgt;
        const int n4 = NC / 4;
        float s = 0.f;
        for (int i = bid * blockDim.x + threadIdx.x; i < n4;
             i += MSE_BLOCKS * blockDim.x) {
            float4 a = p4[i], b = t4[i];
            float dx = a.x - b.x, dy = a.y - b.y, dz = a.z - b.z, dw = a.w - b.w;
            s += dx * dx + dy * dy + dz * dz + dw * dw;
        }
        s = wave_reduce_dpp(s);

        __shared__ float bsum[4];
        if (lane == 63) bsum[wave] = s;
        __syncthreads();
        if (threadIdx.x == 0) {
            float t = (bsum[0] + bsum[1]) + (bsum[2] + bsum[3]);
            atomicAdd(out, t * (1.0f / (float)NC));
        }
    }
}

extern "C" void kernel_launch(void* const* d_in, const int* in_sizes, int n_in,
                              void* d_out, int out_size, void* d_ws, size_t ws_size,
                              hipStream_t stream) {
    const float* y_pred = (const float*)d_in[0];   // [131072, 64]
    const float* y_feat = (const float*)d_in[1];   // [131072, 512]
    const float* y_true = (const float*)d_in[2];   // [128, 1024, 64]
    float* out = (float*)d_out;

    hipMemsetAsync(out, 0, sizeof(float), stream);
    fused_kernel<<<TOTAL_BLOCKS, 256, 0, stream>>>(y_feat, y_pred, y_true, out);
}

// Round 3
// 65.184 us; speedup vs baseline: 1.8594x; 1.5762x over previous
//
#include <hip/hip_runtime.h>

// Problem constants: N=131072, D=512, C=64, CHUNK=8
#define NC          8388608     // N * C
#define NCHUNK      16384       // N / 8
#define ALPHA       0.1f
#define FEAT_BLOCKS 1536        // 4 waves each -> 6144 feat waves, grid-stride over chunks
#define MSE_BLOCKS  512
#define TOTAL_BLOCKS (FEAT_BLOCKS + MSE_BLOCKS)
#define NSLOT       64
#define SLOT_STRIDE 32          // floats -> each slot on its own 128-B line

// Single v_add_f32 with DPP modifier (rocPRIM wave64 reduce pattern).
template<int ctrl, int rmask>
__device__ __forceinline__ float dpp_add(float v) {
    int t = __builtin_amdgcn_update_dpp(0, __float_as_int(v), ctrl, rmask, 0xf, true);
    return v + __int_as_float(t);
}

// Full 64-lane sum; result valid in lane 63.
__device__ __forceinline__ float wave_reduce_dpp(float v) {
    v = dpp_add<0xB1,  0xf>(v);  // quad_perm xor1
    v = dpp_add<0x4E,  0xf>(v);  // quad_perm xor2
    v = dpp_add<0x141, 0xf>(v);  // row_half_mirror
    v = dpp_add<0x140, 0xf>(v);  // row_mirror
    v = dpp_add<0x142, 0xa>(v);  // row_bcast:15
    v = dpp_add<0x143, 0xc>(v);  // row_bcast:31
    return v;
}

__global__ __launch_bounds__(256) void fused_kernel(const float* __restrict__ feat,
                                                    const float* __restrict__ pred,
                                                    const float* __restrict__ tgt,
                                                    float* __restrict__ ws) {
    const int lane = threadIdx.x & 63;
    const int wave = threadIdx.x >> 6;
    __shared__ float bsum[4];
    float block_val;   // value to atomically add (computed on threadIdx.x==0)

    if (blockIdx.x < FEAT_BLOCKS) {
        // ---- feat_dist: one wave per 8x512 chunk, grid-stride over chunks ----
        const int wid = blockIdx.x * 4 + wave;
        float wacc = 0.f;                     // per-wave accumulator (lane 63)
        for (int chunk = wid; chunk < NCHUNK; chunk += FEAT_BLOCKS * 4) {
            const float4* base = (const float4*)(feat + (size_t)chunk * 8 * 512);
            float a[8][8];
            #pragma unroll
            for (int i = 0; i < 8; ++i) {
                float4 v1 = base[i * 128 + lane];
                float4 v2 = base[i * 128 + 64 + lane];
                a[i][0] = v1.x; a[i][1] = v1.y; a[i][2] = v1.z; a[i][3] = v1.w;
                a[i][4] = v2.x; a[i][5] = v2.y; a[i][6] = v2.z; a[i][7] = v2.w;
            }

            // 36 upper-tri (incl. diag) per-lane partial dots.
            float p[36];
            #pragma unroll
            for (int i = 0; i < 8; ++i) {
                #pragma unroll
                for (int j = i; j < 8; ++j) {
                    const int idx = 8 * i - (i * (i - 1)) / 2 + (j - i);
                    float s = 0.f;
                    #pragma unroll
                    for (int k = 0; k < 8; ++k) s = fmaf(a[i][k], a[j][k], s);
                    p[idx] = s;
                }
            }

            // Cross-lane sum of all 36 partials, pure-VALU DPP.
            #pragma unroll
            for (int k = 0; k < 36; ++k) p[k] = wave_reduce_dpp(p[k]);

            if (lane == 63) {
                const int diag[8] = {0, 8, 15, 21, 26, 30, 33, 35};
                float rn[8];
                #pragma unroll
                for (int i = 0; i < 8; ++i) rn[i] = rsqrtf(p[diag[i]]);
                float acc = 0.f;
                #pragma unroll
                for (int i = 0; i < 8; ++i) {
                    #pragma unroll
                    for (int j = i + 1; j < 8; ++j) {
                        const int idx = 8 * i - (i * (i - 1)) / 2 + (j - i);
                        acc = fmaf(p[idx], rn[i] * rn[j], acc);
                    }
                }
                wacc += 28.0f - acc;          // sum of (1 - sim) over 28 pairs
            }
        }
        if (lane == 63) bsum[wave] = wacc;
        __syncthreads();
        block_val = ALPHA * ((bsum[0] + bsum[1]) + (bsum[2] + bsum[3]));
    } else {
        // ---- MSE over 8.4M elements, grid-stride float4 ----
        const int bid = blockIdx.x - FEAT_BLOCKS;
        const float4* p4 = (const float4*)pred;
        const float4* t4 = (const float4*)tgt;
        const int n4 = NC / 4;
        float s = 0.f;
        for (int i = bid * blockDim.x + threadIdx.x; i < n4;
             i += MSE_BLOCKS * blockDim.x) {
            float4 a = p4[i], b = t4[i];
            float dx = a.x - b.x, dy = a.y - b.y, dz = a.z - b.z, dw = a.w - b.w;
            s += dx * dx + dy * dy + dz * dz + dw * dw;
        }
        s = wave_reduce_dpp(s);
        if (lane == 63) bsum[wave] = s;
        __syncthreads();
        block_val = ((bsum[0] + bsum[1]) + (bsum[2] + bsum[3])) * (1.0f / (float)NC);
    }

    // One atomic per block, spread across 64 line-separated slots.
    if (threadIdx.x == 0)
        atomicAdd(&ws[(blockIdx.x & (NSLOT - 1)) * SLOT_STRIDE], block_val);
}

// Single wave: sum the 64 slots -> out[0].
__global__ __launch_bounds__(64) void final_reduce(const float* __restrict__ ws,
                                                   float* __restrict__ out) {
    float v = ws[threadIdx.x * SLOT_STRIDE];
    v = wave_reduce_dpp(v);
    if (threadIdx.x == 63) out[0] = v;
}

extern "C" void kernel_launch(void* const* d_in, const int* in_sizes, int n_in,
                              void* d_out, int out_size, void* d_ws, size_t ws_size,
                              hipStream_t stream) {
    const float* y_pred = (const float*)d_in[0];   // [131072, 64]
    const float* y_feat = (const float*)d_in[1];   // [131072, 512]
    const float* y_true = (const float*)d_in[2];   // [128, 1024, 64]
    float* out = (float*)d_out;
    float* ws  = (float*)d_ws;

    hipMemsetAsync(ws, 0, NSLOT * SLOT_STRIDE * sizeof(float), stream);
    fused_kernel<<<TOTAL_BLOCKS, 256, 0, stream>>>(y_feat, y_pred, y_true, ws);
    final_reduce<<<1, 64, 0, stream>>>(ws, out);
}